// Round 2
// baseline (406.680 us; speedup 1.0000x reference)
//
#include <hip/hip_runtime.h>

// y = relu(x @ (w1*m)^T + b1) @ (w2*m^T)^T + b2
// R2: 64 rows/block shared by 4 waves, chunk=64 hidden col-split 4 ways.
// Weights pre-swizzled to MFMA B-frag order; each weight byte read from LDS
// once per BLOCK (was once per wave) -> LDS read traffic 8.9 GB -> 3.1 GB.

#define D_MODEL 256
#define D_HID   1024
#define MT      64               // rows per block
#define CHUNK   64               // hidden units per chunk
#define NCHUNK  (D_HID / CHUNK)  // 16
#define CHUNK_ELEMS (CHUNK * D_MODEL)  // 16384 bf16 elems = 32 KB
#define SH_STRIDE 72             // halfwords; 144 B = 9*16 -> b128-aligned, conflict-free

typedef __attribute__((ext_vector_type(8))) short short8;
typedef __attribute__((ext_vector_type(4))) float v4f;

__device__ __forceinline__ unsigned short f2bf(float f) {
  union { float f; unsigned int u; } v; v.f = f;
  unsigned int u = v.u;
  return (unsigned short)((u + 0x7FFFu + ((u >> 16) & 1u)) >> 16);  // RNE
}

__device__ __forceinline__ void async16(void* lds, const void* g) {
  __builtin_amdgcn_global_load_lds(
      (const __attribute__((address_space(1))) unsigned int*)g,
      (__attribute__((address_space(3))) unsigned int*)lds,
      16, 0, 0);
}

// ---------------- prep: mask+cast+swizzle weights into B-frag order ----------
// W1p: chunk c (64 hidden x 256 k), frag (cg 0..3, kk 0..7):
//   elem offset c*16384 + ((cg*8+kk)*64 + lane)*8 + j
//   holds W1eff[h = c*64 + cg*16 + (lane&15)][k = kk*32 + (lane>>4)*8 + j]
// W2p: chunk c (256 n x 64 h), frag (nt 0..15, ks 0..1):
//   elem offset c*16384 + ((nt*2+ks)*64 + lane)*8 + j
//   holds W2eff[n = nt*16 + (lane&15)][h = c*64 + ks*32 + (lane>>4)*8 + j]
__global__ __launch_bounds__(256) void prep_weights(
    const float* __restrict__ w1, const float* __restrict__ w2,
    const int* __restrict__ mask,
    unsigned short* __restrict__ W1p, unsigned short* __restrict__ W2p)
{
  int t = blockIdx.x * 256 + threadIdx.x;   // 0..65535
  if (t < 32768) {
    int c    = t >> 11;
    int r    = t & 2047;
    int cg   = r >> 9;
    int kk   = (r >> 6) & 7;
    int lane = r & 63;
    int h = c * 64 + cg * 16 + (lane & 15);
    int k = kk * 32 + (lane >> 4) * 8;
    const float* wp = w1 + h * 256 + k;
    const int*   mp = mask + h * 256 + k;
    short8 v;
    #pragma unroll
    for (int j = 0; j < 8; ++j) v[j] = (short)(mp[j] ? f2bf(wp[j]) : 0);
    *(short8*)(W1p + (size_t)t * 8) = v;
  } else {
    int s    = t - 32768;
    int c    = s >> 11;
    int r    = s & 2047;
    int nt   = r >> 7;
    int ks   = (r >> 6) & 1;
    int lane = r & 63;
    int n = nt * 16 + (lane & 15);
    int h = c * 64 + ks * 32 + (lane >> 4) * 8;
    const float* wp = w2 + n * 1024 + h;
    short8 v;
    #pragma unroll
    for (int j = 0; j < 8; ++j)
      v[j] = (short)(mask[(h + j) * 256 + n] ? f2bf(wp[j]) : 0);
    *(short8*)(W2p + (size_t)s * 8) = v;
  }
}

// ---------------- fused main kernel ----------------
__global__ __launch_bounds__(256, 2) void ffd_fused(
    const float* __restrict__ X, const float* __restrict__ b1,
    const float* __restrict__ b2,
    const unsigned short* __restrict__ W1p, const unsigned short* __restrict__ W2p,
    float* __restrict__ Y)
{
  __shared__ alignas(16) unsigned short sW1[CHUNK_ELEMS];     // 32 KB
  __shared__ alignas(16) unsigned short sW2[CHUNK_ELEMS];     // 32 KB
  __shared__ alignas(16) unsigned short sH[MT * SH_STRIDE];   // 9 KB

  const int tid  = threadIdx.x;
  const int lane = tid & 63;
  const int cg   = tid >> 6;     // wave id = column-group
  const int l16  = lane & 15;
  const int q    = lane >> 4;

  const long rowBase = (long)blockIdx.x * MT;

  // X A-fragments for ALL 64 rows, K=256, in registers:
  //   xf[rf][kk][j] = X[rowBase + rf*16 + l16][kk*32 + q*8 + j]   (128 VGPRs)
  short8 xf[4][8];
  #pragma unroll
  for (int rf = 0; rf < 4; ++rf) {
    const float* xrow = X + (rowBase + rf * 16 + l16) * D_MODEL;
    #pragma unroll
    for (int kk = 0; kk < 8; ++kk) {
      const float4 f0 = *(const float4*)(xrow + kk * 32 + q * 8);
      const float4 f1 = *(const float4*)(xrow + kk * 32 + q * 8 + 4);
      short8 v;
      v[0] = (short)f2bf(f0.x); v[1] = (short)f2bf(f0.y);
      v[2] = (short)f2bf(f0.z); v[3] = (short)f2bf(f0.w);
      v[4] = (short)f2bf(f1.x); v[5] = (short)f2bf(f1.y);
      v[6] = (short)f2bf(f1.z); v[7] = (short)f2bf(f1.w);
      xf[rf][kk] = v;
    }
  }

  v4f acc[4][4];   // [rf][ntl] : 64 rows x 64 out-cols (this wave's slice)
  #pragma unroll
  for (int rf = 0; rf < 4; ++rf)
    #pragma unroll
    for (int ntl = 0; ntl < 4; ++ntl)
      acc[rf][ntl] = (v4f){0.f, 0.f, 0.f, 0.f};

  #pragma unroll 1
  for (int c = 0; c < NCHUNK; ++c) {
    __syncthreads();   // all waves done reading sW1/sW2/sH of previous chunk
    {
      const unsigned short* g1 = W1p + (size_t)c * CHUNK_ELEMS + tid * 8;
      const unsigned short* g2 = W2p + (size_t)c * CHUNK_ELEMS + tid * 8;
      #pragma unroll
      for (int i = 0; i < 8; ++i) {
        async16(&sW1[i * 2048 + tid * 8], g1 + i * 2048);
        async16(&sW2[i * 2048 + tid * 8], g2 + i * 2048);
      }
    }
    const float bb = b1[c * CHUNK + cg * 16 + l16];
    __syncthreads();   // staging drained (compiler emits vmcnt(0) before barrier)

    // fc1: this wave computes hidden slice [cg*16, cg*16+16) for all 64 rows
    v4f hacc[4];
    #pragma unroll
    for (int rf = 0; rf < 4; ++rf) hacc[rf] = (v4f){0.f, 0.f, 0.f, 0.f};
    #pragma unroll
    for (int kk = 0; kk < 8; ++kk) {
      short8 bf = *(const short8*)&sW1[(cg * 8 + kk) * 512 + lane * 8];
      #pragma unroll
      for (int rf = 0; rf < 4; ++rf)
        hacc[rf] = __builtin_amdgcn_mfma_f32_16x16x32_bf16(xf[rf][kk], bf, hacc[rf], 0, 0, 0);
    }

    // bias + relu -> shared H tile (row-major bf16, stride 72 halfwords)
    #pragma unroll
    for (int rf = 0; rf < 4; ++rf) {
      #pragma unroll
      for (int r = 0; r < 4; ++r) {
        float v = hacc[rf][r] + bb;
        v = v > 0.f ? v : 0.f;
        sH[(rf * 16 + q * 4 + r) * SH_STRIDE + cg * 16 + l16] = f2bf(v);
      }
    }
    __syncthreads();   // sH complete (cross-wave: fc2 reads all column groups)

    // fc2: acc[64 rows][this wave's 64 cols] += H(64x64) @ W2c^T
    #pragma unroll
    for (int ks = 0; ks < 2; ++ks) {
      short8 af[4];
      #pragma unroll
      for (int rf = 0; rf < 4; ++rf)
        af[rf] = *(const short8*)&sH[(rf * 16 + l16) * SH_STRIDE + ks * 32 + q * 8];
      #pragma unroll
      for (int ntl = 0; ntl < 4; ++ntl) {
        short8 bf = *(const short8*)&sW2[((cg * 4 + ntl) * 2 + ks) * 512 + lane * 8];
        #pragma unroll
        for (int rf = 0; rf < 4; ++rf)
          acc[rf][ntl] = __builtin_amdgcn_mfma_f32_16x16x32_bf16(af[rf], bf, acc[rf][ntl], 0, 0, 0);
      }
    }
  }

  // epilogue: + b2, store fp32
  #pragma unroll
  for (int ntl = 0; ntl < 4; ++ntl) {
    int col = (cg * 4 + ntl) * 16 + l16;
    float bias = b2[col];
    #pragma unroll
    for (int rf = 0; rf < 4; ++rf) {
      #pragma unroll
      for (int r = 0; r < 4; ++r) {
        long row = rowBase + rf * 16 + q * 4 + r;
        Y[row * D_MODEL + col] = acc[rf][ntl][r] + bias;
      }
    }
  }
}

extern "C" void kernel_launch(void* const* d_in, const int* in_sizes, int n_in,
                              void* d_out, int out_size, void* d_ws, size_t ws_size,
                              hipStream_t stream) {
  const float* x    = (const float*)d_in[0];
  const float* w1   = (const float*)d_in[1];
  const float* b1   = (const float*)d_in[2];
  const float* w2   = (const float*)d_in[3];
  const float* b2   = (const float*)d_in[4];
  const int*   mask = (const int*)d_in[5];

  unsigned short* W1p = (unsigned short*)d_ws;          // 512 KB
  unsigned short* W2p = W1p + (size_t)D_HID * D_MODEL;  // 512 KB
  float* Y = (float*)d_out;

  prep_weights<<<256, 256, 0, stream>>>(w1, w2, mask, W1p, W2p);
  ffd_fused<<<131072 / MT, 256, 0, stream>>>(x, b1, b2, W1p, W2p, Y);
}